// Round 1
// baseline (350.853 us; speedup 1.0000x reference)
//
#include <hip/hip_runtime.h>
#include <float.h>
#include <math.h>

// Problem dims (fixed by setup_inputs): [16, 1, 352, 1216] float32
#define BN 16
#define BH 352
#define BW 1216
#define W4 (BW / 4)            // 304 float4 per row
#define NF4 (BN * BH * W4)     // 1,712,128 float4 total
#define MIND 0.1f
#define MAXD 100.0f

// ---------------- horizontal max/min pass (radius R <= 4), optional input inversion ---------
template<int R, bool ISMAX, bool INVERT>
__global__ __launch_bounds__(256) void hpass_k(const float4* __restrict__ in,
                                               float4* __restrict__ out) {
    int id = blockIdx.x * 256 + threadIdx.x;
    if (id >= NF4) return;
    int x4 = id % W4;
    const float ident = ISMAX ? -FLT_MAX : FLT_MAX;
    float4 fill = make_float4(ident, ident, ident, ident);
    float4 L  = (x4 > 0)      ? in[id - 1] : fill;
    float4 M  = in[id];
    float4 Rg = (x4 < W4 - 1) ? in[id + 1] : fill;
    float t[12] = {L.x, L.y, L.z, L.w, M.x, M.y, M.z, M.w, Rg.x, Rg.y, Rg.z, Rg.w};
    if (INVERT) {
        // invert: v>0.1 ? 100-v : v   (identity values pass through: -FLT_MAX > 0.1 is false)
        #pragma unroll
        for (int i = 0; i < 12; ++i) {
            float v = t[i];
            t[i] = (v > MIND) ? (MAXD - v) : v;
        }
    }
    auto wred = [&](int base) {
        float acc = t[base - R];
        #pragma unroll
        for (int d = -R + 1; d <= R; ++d) {
            float v = t[base + d];
            acc = ISMAX ? fmaxf(acc, v) : fminf(acc, v);
        }
        return acc;
    };
    out[id] = make_float4(wred(4), wred(5), wred(6), wred(7));
}

// ---------------- vertical max/min pass (radius R <= 4), optional fill-select ---------------
// SELECT: out = (sel < 0.1) ? vmax : sel   (fill-empty step)
template<int R, bool ISMAX, bool SELECT>
__global__ __launch_bounds__(256) void vpass_k(const float4* __restrict__ in,
                                               const float4* __restrict__ sel,
                                               float4* __restrict__ out) {
    int id = blockIdx.x * 256 + threadIdx.x;
    if (id >= NF4) return;
    int y = (id / W4) % BH;
    const float ident = ISMAX ? -FLT_MAX : FLT_MAX;
    float ax = ident, ay = ident, az = ident, aw = ident;
    #pragma unroll
    for (int d = -R; d <= R; ++d) {
        int yy = y + d;
        if (yy >= 0 && yy < BH) {
            float4 v = in[id + d * W4];
            if (ISMAX) { ax = fmaxf(ax, v.x); ay = fmaxf(ay, v.y); az = fmaxf(az, v.z); aw = fmaxf(aw, v.w); }
            else       { ax = fminf(ax, v.x); ay = fminf(ay, v.y); az = fminf(az, v.z); aw = fminf(aw, v.w); }
        }
    }
    float4 o = make_float4(ax, ay, az, aw);
    if (SELECT) {
        float4 c = sel[id];
        o.x = (c.x < MIND) ? o.x : c.x;
        o.y = (c.y < MIND) ? o.y : c.y;
        o.z = (c.z < MIND) ? o.z : c.z;
        o.w = (c.w < MIND) ? o.w : c.w;
    }
    out[id] = o;
}

// ---------------- 5x5 median, zero padding (exact 13th of 25) --------------------------------
__global__ __launch_bounds__(256) void median_k(const float4* __restrict__ in,
                                                float4* __restrict__ out) {
    int id = blockIdx.x * 256 + threadIdx.x;
    if (id >= NF4) return;
    int x4 = id % W4;
    int y = (id / W4) % BH;
    float vals[5][8];
    const float4 z4 = make_float4(0.f, 0.f, 0.f, 0.f);
    #pragma unroll
    for (int r = 0; r < 5; ++r) {
        int yy = y + r - 2;
        bool ok = (yy >= 0) && (yy < BH);
        int rid = id + (r - 2) * W4;
        float4 L  = (ok && x4 > 0)      ? in[rid - 1] : z4;
        float4 M  = ok                  ? in[rid]     : z4;
        float4 Rg = (ok && x4 < W4 - 1) ? in[rid + 1] : z4;
        vals[r][0] = L.z;  vals[r][1] = L.w;
        vals[r][2] = M.x;  vals[r][3] = M.y;  vals[r][4] = M.z;  vals[r][5] = M.w;
        vals[r][6] = Rg.x; vals[r][7] = Rg.y;
    }
    float ov[4];
    #pragma unroll
    for (int i = 0; i < 4; ++i) {
        float v[25];
        #pragma unroll
        for (int r = 0; r < 5; ++r) {
            #pragma unroll
            for (int j = 0; j < 5; ++j)
                v[r * 5 + j] = vals[r][i + j];
        }
        // branchless partial selection sort up to index 12 (median of 25)
        #pragma unroll
        for (int a = 0; a <= 12; ++a) {
            #pragma unroll
            for (int b = a + 1; b < 25; ++b) {
                float lo = fminf(v[a], v[b]);
                float hi = fmaxf(v[a], v[b]);
                v[a] = lo; v[b] = hi;
            }
        }
        ov[i] = v[12];
    }
    out[id] = make_float4(ov[0], ov[1], ov[2], ov[3]);
}

// ---------------- horizontal gaussian (reflect padding) --------------------------------------
__global__ __launch_bounds__(256) void hgauss_k(const float4* __restrict__ in,
                                                float4* __restrict__ out,
                                                float w0, float w1, float w2) {
    int id = blockIdx.x * 256 + threadIdx.x;
    if (id >= NF4) return;
    int x4 = id % W4;
    float4 M = in[id];
    float l0, l1, r0, r1;
    if (x4 > 0)      { float4 L  = in[id - 1]; l0 = L.z;  l1 = L.w; }
    else             { l0 = M.z; l1 = M.y; }           // reflect: col -2 -> 2, col -1 -> 1
    if (x4 < W4 - 1) { float4 Rg = in[id + 1]; r0 = Rg.x; r1 = Rg.y; }
    else             { r0 = M.z; r1 = M.y; }           // reflect: 1216 -> 1214, 1217 -> 1213
    float t[8] = {l0, l1, M.x, M.y, M.z, M.w, r0, r1};
    auto g = [&](int c) {
        return w2 * (t[c - 2] + t[c + 2]) + w1 * (t[c - 1] + t[c + 1]) + w0 * t[c];
    };
    out[id] = make_float4(g(2), g(3), g(4), g(5));
}

// ---------------- vertical gaussian (reflect) + valid-select + invert back -------------------
__global__ __launch_bounds__(256) void vgauss_k(const float4* __restrict__ in,   // h-blurred
                                                const float4* __restrict__ dm,   // median output
                                                float4* __restrict__ out,
                                                float w0, float w1, float w2) {
    int id = blockIdx.x * 256 + threadIdx.x;
    if (id >= NF4) return;
    int y = (id / W4) % BH;
    float wv[5] = {w2, w1, w0, w1, w2};
    float ax = 0.f, ay = 0.f, az = 0.f, aw = 0.f;
    #pragma unroll
    for (int d = -2; d <= 2; ++d) {
        int yy = y + d;
        yy = (yy < 0) ? -yy : yy;
        yy = (yy >= BH) ? (2 * BH - 2 - yy) : yy;
        float4 v = in[id + (yy - y) * W4];
        float wd = wv[d + 2];
        ax = fmaf(wd, v.x, ax); ay = fmaf(wd, v.y, ay);
        az = fmaf(wd, v.z, az); aw = fmaf(wd, v.w, aw);
    }
    float4 c = dm[id];
    auto fin = [&](float cc, float bl) {
        float s = (cc > MIND) ? bl : cc;   // use blurred only on valid pixels
        return (s > MIND) ? (MAXD - s) : s; // invert back
    };
    out[id] = make_float4(fin(c.x, ax), fin(c.y, ay), fin(c.z, az), fin(c.w, aw));
}

extern "C" void kernel_launch(void* const* d_in, const int* in_sizes, int n_in,
                              void* d_out, int out_size, void* d_ws, size_t ws_size,
                              hipStream_t stream) {
    const float4* in = (const float4*)d_in[0];
    float4* O = (float4*)d_out;
    float4* A = (float4*)d_ws;
    float4* B = A + NF4;          // needs 2 * NF4 * 16B = 54.8 MB of ws

    dim3 grid((NF4 + 255) / 256), blk(256);

    // Gaussian weights in f32, matching jax: sigma = 1.1 (double), 2*sigma^2 = 2.4200000000000004
    float c2 = (float)2.4200000000000004;
    float e1 = expf(-1.0f / c2);
    float e4 = expf(-4.0f / c2);
    float s  = 1.0f + 2.0f * e1 + 2.0f * e4;
    float w0 = 1.0f / s, w1 = e1 / s, w2 = e4 / s;

    // 1-2: dilate5(dilate5(invert(x))) == dilate9(invert(x))
    hpass_k<4, true , true ><<<grid, blk, 0, stream>>>(in, A);
    vpass_k<4, true , false><<<grid, blk, 0, stream>>>(A, nullptr, B);
    // 3-4: erode5 (closing)
    hpass_k<2, false, false><<<grid, blk, 0, stream>>>(B, A);
    vpass_k<2, false, false><<<grid, blk, 0, stream>>>(A, nullptr, B);
    // 5-6: dilate7 + fill empty (select against closed map B) -> d_out (scratch)
    hpass_k<3, true , false><<<grid, blk, 0, stream>>>(B, A);
    vpass_k<3, true , true ><<<grid, blk, 0, stream>>>(A, B, O);
    // 7: 5x5 median (zero pad)
    median_k<<<grid, blk, 0, stream>>>(O, A);
    // 8-9: gaussian blur (reflect) + valid-select + invert back
    hgauss_k<<<grid, blk, 0, stream>>>(A, B, w0, w1, w2);
    vgauss_k<<<grid, blk, 0, stream>>>(B, A, O, w0, w1, w2);
}

// Round 2
// 193.539 us; speedup vs baseline: 1.8128x; 1.8128x over previous
//
#include <hip/hip_runtime.h>
#include <float.h>

#define IW 1216
#define IH 352
#define W4 304                  // float4 per row
#define NF4 (16 * IH * W4)      // 1,712,128
#define MIND 0.1f
#define MAXD 100.0f

__device__ __forceinline__ float4 vmax4(float4 a, float4 b) {
    return make_float4(fmaxf(a.x,b.x), fmaxf(a.y,b.y), fmaxf(a.z,b.z), fmaxf(a.w,b.w));
}
__device__ __forceinline__ float4 vmin4(float4 a, float4 b) {
    return make_float4(fminf(a.x,b.x), fminf(a.y,b.y), fminf(a.z,b.z), fminf(a.w,b.w));
}

// ============================================================================
// K1: fused morphology: invert -> dilate9 (=dilate5∘dilate5) -> erode5 -> dilate7+fill
// 2D tile 128x32 out, halo 9; LDS ping-pong 2x [50][152] floats = 60.8 KB
// ============================================================================
__global__ __launch_bounds__(256) void morph_k(const float4* __restrict__ in,
                                               float4* __restrict__ out) {
    __shared__ float A_[50][152];
    __shared__ float B_[50][152];
    int b  = blockIdx.x;
    int sw = (b & 7) * 220 + (b >> 3);          // XCD chunk swizzle (1760 = 8*220)
    int tx = sw % 10; int t2 = sw / 10;
    int ty = t2 % 11; int n  = t2 / 11;
    int x0 = tx * 128, y0 = ty * 32;
    int tid = threadIdx.x;
    const int base4 = (x0 >> 2) - 3;
    const long ib = (long)n * IH * W4;

    // ---- load + invert; OOB -> -FLT_MAX (dilate identity) ----
    for (int i = tid; i < 50 * 38; i += 256) {
        int r = i / 38, c4 = i % 38;
        int gy = y0 - 9 + r; int gx4 = base4 + c4;
        float4 v;
        if ((unsigned)gy < IH && (unsigned)gx4 < (unsigned)W4) {
            v = in[ib + gy * W4 + gx4];
            v.x = v.x > MIND ? MAXD - v.x : v.x;
            v.y = v.y > MIND ? MAXD - v.y : v.y;
            v.z = v.z > MIND ? MAXD - v.z : v.z;
            v.w = v.w > MIND ? MAXD - v.w : v.w;
        } else { v.x = v.y = v.z = v.w = -FLT_MAX; }
        *(float4*)&A_[r][c4 * 4] = v;
    }
    __syncthreads();

    // ---- h-dilate9 (r4): rows 0..49, cols 4..147 -> B ----
    for (int i = tid; i < 50 * 36; i += 256) {
        int r = i / 36, c = ((i % 36) + 1) * 4;
        float t[12];
        *(float4*)&t[0] = *(float4*)&A_[r][c - 4];
        *(float4*)&t[4] = *(float4*)&A_[r][c];
        *(float4*)&t[8] = *(float4*)&A_[r][c + 4];
        float cm  = fmaxf(fmaxf(fmaxf(t[3],t[4]), fmaxf(t[5],t[6])), fmaxf(t[7],t[8]));
        float m12 = fmaxf(t[1], t[2]);
        float m910= fmaxf(t[9], t[10]);
        float4 o;
        o.x = fmaxf(fmaxf(cm, t[0]),  m12);
        o.y = fmaxf(fmaxf(cm, t[9]),  m12);
        o.z = fmaxf(fmaxf(cm, t[2]),  m910);
        o.w = fmaxf(fmaxf(cm, t[11]), m910);
        *(float4*)&B_[r][c] = o;
    }
    __syncthreads();

    // ---- v-dilate9: rows 4..45 -> A ----
    for (int i = tid; i < 42 * 36; i += 256) {
        int r = i / 36 + 4, c = ((i % 36) + 1) * 4;
        float4 m = *(float4*)&B_[r - 4][c];
        #pragma unroll
        for (int d = -3; d <= 4; ++d) m = vmax4(m, *(float4*)&B_[r + d][c]);
        *(float4*)&A_[r][c] = m;
    }
    __syncthreads();

    // ---- cleanup: globally-OOB cells -> +FLT_MAX (erode identity) ----
    for (int i = tid; i < 42 * 36; i += 256) {
        int r = i / 36 + 4, c = ((i % 36) + 1) * 4;
        int gy = y0 - 9 + r; int gxb = x0 - 12 + c;
        bool rok = (unsigned)gy < IH;
        float4 v = *(float4*)&A_[r][c];
        v.x = (rok && (unsigned)(gxb + 0) < IW) ? v.x : FLT_MAX;
        v.y = (rok && (unsigned)(gxb + 1) < IW) ? v.y : FLT_MAX;
        v.z = (rok && (unsigned)(gxb + 2) < IW) ? v.z : FLT_MAX;
        v.w = (rok && (unsigned)(gxb + 3) < IW) ? v.w : FLT_MAX;
        *(float4*)&A_[r][c] = v;
    }
    __syncthreads();

    // ---- h-erode5 (r2): rows 4..45, cols 8..143 -> B ----
    for (int i = tid; i < 42 * 34; i += 256) {
        int r = i / 34 + 4, c = ((i % 34) + 2) * 4;
        float t[12];
        *(float4*)&t[0] = *(float4*)&A_[r][c - 4];
        *(float4*)&t[4] = *(float4*)&A_[r][c];
        *(float4*)&t[8] = *(float4*)&A_[r][c + 4];
        float m34 = fminf(t[3], t[4]), m56 = fminf(t[5], t[6]), m78 = fminf(t[7], t[8]);
        float s  = fminf(m34, m56), s2 = fminf(m56, m78);
        float4 o;
        o.x = fminf(s,  t[2]);
        o.y = fminf(s,  t[7]);
        o.z = fminf(t[4], s2);
        o.w = fminf(s2, t[9]);
        *(float4*)&B_[r][c] = o;
    }
    __syncthreads();

    // ---- v-erode5: rows 6..43 -> A (closing) ----
    for (int i = tid; i < 38 * 34; i += 256) {
        int r = i / 34 + 6, c = ((i % 34) + 2) * 4;
        float4 m = *(float4*)&B_[r - 2][c];
        #pragma unroll
        for (int d = -1; d <= 2; ++d) m = vmin4(m, *(float4*)&B_[r + d][c]);
        *(float4*)&A_[r][c] = m;
    }
    __syncthreads();

    // ---- cleanup: OOB -> -FLT_MAX (dilate7 identity) ----
    for (int i = tid; i < 38 * 34; i += 256) {
        int r = i / 34 + 6, c = ((i % 34) + 2) * 4;
        int gy = y0 - 9 + r; int gxb = x0 - 12 + c;
        bool rok = (unsigned)gy < IH;
        float4 v = *(float4*)&A_[r][c];
        v.x = (rok && (unsigned)(gxb + 0) < IW) ? v.x : -FLT_MAX;
        v.y = (rok && (unsigned)(gxb + 1) < IW) ? v.y : -FLT_MAX;
        v.z = (rok && (unsigned)(gxb + 2) < IW) ? v.z : -FLT_MAX;
        v.w = (rok && (unsigned)(gxb + 3) < IW) ? v.w : -FLT_MAX;
        *(float4*)&A_[r][c] = v;
    }
    __syncthreads();

    // ---- h-dilate7 (r3): rows 6..43, cols 12..139 -> B ----
    for (int i = tid; i < 38 * 32; i += 256) {
        int r = i / 32 + 6, c = ((i % 32) + 3) * 4;
        float t[12];
        *(float4*)&t[0] = *(float4*)&A_[r][c - 4];
        *(float4*)&t[4] = *(float4*)&A_[r][c];
        *(float4*)&t[8] = *(float4*)&A_[r][c + 4];
        float m23 = fmaxf(t[2], t[3]), m45 = fmaxf(t[4], t[5]);
        float m67 = fmaxf(t[6], t[7]), m89 = fmaxf(t[8], t[9]);
        float s = fmaxf(m45, m67);
        float sm23 = fmaxf(s, m23), sm89 = fmaxf(s, m89);
        float4 o;
        o.x = fmaxf(sm23, t[1]);
        o.y = fmaxf(sm23, t[8]);
        o.z = fmaxf(sm89, t[3]);
        o.w = fmaxf(sm89, t[10]);
        *(float4*)&B_[r][c] = o;
    }
    __syncthreads();

    // ---- v-dilate7 + fill-select + store: rows 9..40 ----
    for (int i = tid; i < 32 * 32; i += 256) {
        int r = i / 32 + 9, c = ((i % 32) + 3) * 4;
        float4 m = *(float4*)&B_[r - 3][c];
        #pragma unroll
        for (int d = -2; d <= 3; ++d) m = vmax4(m, *(float4*)&B_[r + d][c]);
        float4 cl = *(float4*)&A_[r][c];
        float4 o;
        o.x = cl.x < MIND ? m.x : cl.x;
        o.y = cl.y < MIND ? m.y : cl.y;
        o.z = cl.z < MIND ? m.z : cl.z;
        o.w = cl.w < MIND ? m.w : cl.w;
        int gy = y0 + r - 9;
        int gx4 = (x0 >> 2) + ((c - 12) >> 2);
        if (gx4 < W4) out[ib + gy * W4 + gx4] = o;
    }
}

// ============================================================================
// K2: 5x5 median, zero padding. Column-sort sharing + doubly-sorted-matrix
// candidate selection (rank-7 of 13 feasible positions), forgetful network.
// ============================================================================
#define CE(a,b) { float _l = fminf(a,b), _h = fmaxf(a,b); a = _l; b = _h; }
#define SORT5(a,b,c,d,e) { CE(a,b) CE(d,e) CE(c,e) CE(c,d) CE(a,d) CE(a,c) CE(b,e) CE(b,d) CE(b,c) }
#define MM8(s0,s1,s2,s3,s4,s5,s6,s7) { CE(s0,s1) CE(s2,s3) CE(s4,s5) CE(s6,s7) \
    CE(s0,s2) CE(s0,s4) CE(s0,s6) CE(s1,s7) CE(s3,s7) CE(s5,s7) }
#define MM7(s0,s1,s2,s3,s4,s5,s6) { CE(s0,s1) CE(s2,s3) CE(s4,s5) \
    CE(s0,s2) CE(s0,s4) CE(s0,s6) CE(s1,s6) CE(s3,s6) CE(s5,s6) }

__global__ __launch_bounds__(256) void median_k(const float4* __restrict__ in,
                                                float4* __restrict__ out) {
    int b  = blockIdx.x;
    int sb = (b & 7) * 836 + (b >> 3);          // XCD chunk swizzle (6688 = 8*836)
    int id = sb * 256 + threadIdx.x;            // NF4 = 6688*256 exactly
    int x4 = id % W4;
    int y  = (id / W4) % IH;

    float c8[8][5];
    const float4 z4 = make_float4(0.f, 0.f, 0.f, 0.f);
    #pragma unroll
    for (int r = 0; r < 5; ++r) {
        int yy = y + r - 2;
        bool ok = (unsigned)yy < IH;
        int rid = id + (r - 2) * W4;
        float4 L = (ok && x4 > 0)      ? in[rid - 1] : z4;
        float4 M = ok                  ? in[rid]     : z4;
        float4 R = (ok && x4 < W4 - 1) ? in[rid + 1] : z4;
        c8[0][r] = L.z; c8[1][r] = L.w;
        c8[2][r] = M.x; c8[3][r] = M.y; c8[4][r] = M.z; c8[5][r] = M.w;
        c8[6][r] = R.x; c8[7][r] = R.y;
    }
    #pragma unroll
    for (int j = 0; j < 8; ++j) SORT5(c8[j][0], c8[j][1], c8[j][2], c8[j][3], c8[j][4]);

    float res[4];
    #pragma unroll
    for (int p = 0; p < 4; ++p) {
        float m[5][5];
        #pragma unroll
        for (int i2 = 0; i2 < 5; ++i2) {
            #pragma unroll
            for (int j = 0; j < 5; ++j) m[i2][j] = c8[p + j][i2];
            SORT5(m[i2][0], m[i2][1], m[i2][2], m[i2][3], m[i2][4]);
        }
        // 13 feasible positions of doubly-sorted 5x5 for rank 13 of 25
        float s0 = m[0][3], s1 = m[0][4], s2 = m[1][2], s3 = m[1][3];
        float s4 = m[1][4], s5 = m[2][1], s6 = m[2][2], s7 = m[2][3];
        MM8(s0,s1,s2,s3,s4,s5,s6,s7)           // drop min,max
        s0 = m[3][0]; s7 = m[3][1];
        MM8(s0,s1,s2,s3,s4,s5,s6,s7)
        s0 = m[3][2]; s7 = m[4][0];
        MM8(s0,s1,s2,s3,s4,s5,s6,s7)
        s0 = m[4][1];                          // 7 live: s0..s6
        MM7(s0,s1,s2,s3,s4,s5,s6)              // drop min,max -> live s1..s5, need median5
        CE(s1,s2) CE(s3,s4) CE(s1,s3) CE(s2,s4)  // s1=min4 drop, s4=max4 drop
        float mn = fminf(s2, s3), mx = fmaxf(s2, s3);
        res[p] = fmaxf(mn, fminf(mx, s5));     // med3(s2,s3,s5)
    }
    out[id] = make_float4(res[0], res[1], res[2], res[3]);
}

// ============================================================================
// K3: gaussian blur 5 (reflect) + valid-select + invert back, fused h+v via LDS
// ============================================================================
__global__ __launch_bounds__(256) void gauss_k(const float* __restrict__ dm,
                                               float4* __restrict__ out,
                                               float w0, float w1, float w2) {
    __shared__ float A3[36][136];
    __shared__ float B3[36][136];
    int b  = blockIdx.x;
    int sw = (b & 7) * 220 + (b >> 3);
    int tx = sw % 10; int t2 = sw / 10;
    int ty = t2 % 11; int n  = t2 / 11;
    int x0 = tx * 128, y0 = ty * 32;
    int tid = threadIdx.x;
    const long ibF = (long)n * IH * IW;

    // ---- load with reflect padding ----
    for (int i = tid; i < 36 * 34; i += 256) {
        int r = i / 34, c4 = i % 34;
        int gy = y0 - 2 + r;
        gy = gy < 0 ? -gy : (gy >= IH ? 2 * IH - 2 - gy : gy);
        int gxb = x0 - 4 + c4 * 4;
        float4 v;
        if (gxb >= 0 && gxb + 3 < IW) {
            v = *(const float4*)&dm[ibF + (long)gy * IW + gxb];
        } else {
            float* pv = &v.x;
            #pragma unroll
            for (int k = 0; k < 4; ++k) {
                int gx = gxb + k;
                gx = gx < 0 ? -gx : (gx >= IW ? 2 * IW - 2 - gx : gx);
                pv[k] = dm[ibF + (long)gy * IW + gx];
            }
        }
        *(float4*)&A3[r][c4 * 4] = v;
    }
    __syncthreads();

    // ---- h-gauss: rows 0..35, cols 4..131 -> B ----
    for (int i = tid; i < 36 * 32; i += 256) {
        int r = i / 32, c = ((i % 32) + 1) * 4;
        float t[12];
        *(float4*)&t[0] = *(float4*)&A3[r][c - 4];
        *(float4*)&t[4] = *(float4*)&A3[r][c];
        *(float4*)&t[8] = *(float4*)&A3[r][c + 4];
        float4 o;
        o.x = w2 * (t[2] + t[6]) + w1 * (t[3] + t[5]) + w0 * t[4];
        o.y = w2 * (t[3] + t[7]) + w1 * (t[4] + t[6]) + w0 * t[5];
        o.z = w2 * (t[4] + t[8]) + w1 * (t[5] + t[7]) + w0 * t[6];
        o.w = w2 * (t[5] + t[9]) + w1 * (t[6] + t[8]) + w0 * t[7];
        *(float4*)&B3[r][c] = o;
    }
    __syncthreads();

    // ---- v-gauss + select + invert + store: rows 2..33 ----
    for (int i = tid; i < 32 * 32; i += 256) {
        int r = i / 32 + 2, c = ((i % 32) + 1) * 4;
        float4 a = *(float4*)&B3[r - 2][c];
        float4 bb = *(float4*)&B3[r - 1][c];
        float4 cm = *(float4*)&B3[r][c];
        float4 d  = *(float4*)&B3[r + 1][c];
        float4 e  = *(float4*)&B3[r + 2][c];
        float4 bl;
        bl.x = w2 * (a.x + e.x) + w1 * (bb.x + d.x) + w0 * cm.x;
        bl.y = w2 * (a.y + e.y) + w1 * (bb.y + d.y) + w0 * cm.y;
        bl.z = w2 * (a.z + e.z) + w1 * (bb.z + d.z) + w0 * cm.z;
        bl.w = w2 * (a.w + e.w) + w1 * (bb.w + d.w) + w0 * cm.w;
        float4 med = *(float4*)&A3[r][c];
        float4 o;
        { float s = med.x > MIND ? bl.x : med.x; o.x = s > MIND ? MAXD - s : s; }
        { float s = med.y > MIND ? bl.y : med.y; o.y = s > MIND ? MAXD - s : s; }
        { float s = med.z > MIND ? bl.z : med.z; o.z = s > MIND ? MAXD - s : s; }
        { float s = med.w > MIND ? bl.w : med.w; o.w = s > MIND ? MAXD - s : s; }
        int gy = y0 + r - 2;
        int gx4 = (x0 >> 2) + ((c - 4) >> 2);
        if (gx4 < W4) out[(long)n * IH * W4 + gy * W4 + gx4] = o;
    }
}

extern "C" void kernel_launch(void* const* d_in, const int* in_sizes, int n_in,
                              void* d_out, int out_size, void* d_ws, size_t ws_size,
                              hipStream_t stream) {
    const float4* in = (const float4*)d_in[0];
    float4* W1 = (float4*)d_ws;
    float4* W2 = W1 + NF4;      // 2 * NF4 * 16B = 54.8 MB workspace
    float4* O  = (float4*)d_out;

    // Gaussian weights: sigma = 1.1 -> 2*sigma^2 = 2.42 (f32, matching jax f32 math)
    float c2 = 2.42f;
    float e1 = expf(-1.0f / c2);
    float e4 = expf(-4.0f / c2);
    float s  = 1.0f + 2.0f * e1 + 2.0f * e4;
    float w0 = 1.0f / s, w1 = e1 / s, w2 = e4 / s;

    morph_k <<<dim3(1760), dim3(256), 0, stream>>>(in, W1);
    median_k<<<dim3(6688), dim3(256), 0, stream>>>(W1, W2);
    gauss_k <<<dim3(1760), dim3(256), 0, stream>>>((const float*)W2, O, w0, w1, w2);
}

// Round 3
// 182.276 us; speedup vs baseline: 1.9248x; 1.0618x over previous
//
#include <hip/hip_runtime.h>
#include <float.h>
#include <math.h>

#define IW 1216
#define IH 352
#define W4 304
#define MIND 0.1f
#define MAXD 100.0f
// tile: 128 wide x 24 tall output; buffer rows rel -13..36 (ra = rel+13)
#define RB 50

__device__ __forceinline__ float4 vmax4(float4 a, float4 b) {
    return make_float4(fmaxf(a.x,b.x), fmaxf(a.y,b.y), fmaxf(a.z,b.z), fmaxf(a.w,b.w));
}
__device__ __forceinline__ float4 vmin4(float4 a, float4 b) {
    return make_float4(fminf(a.x,b.x), fminf(a.y,b.y), fminf(a.z,b.z), fminf(a.w,b.w));
}

#define CE(a,b) { float _l = fminf(a,b), _h = fmaxf(a,b); a = _l; b = _h; }
#define SORT5(a,b,c,d,e) { CE(a,b) CE(d,e) CE(c,e) CE(c,d) CE(a,d) CE(a,c) CE(b,e) CE(b,d) CE(b,c) }
#define MM8(s0,s1,s2,s3,s4,s5,s6,s7) { CE(s0,s1) CE(s2,s3) CE(s4,s5) CE(s6,s7) \
    CE(s0,s2) CE(s0,s4) CE(s0,s6) CE(s1,s7) CE(s3,s7) CE(s5,s7) }
#define MM7(s0,s1,s2,s3,s4,s5,s6) { CE(s0,s1) CE(s2,s3) CE(s4,s5) \
    CE(s0,s2) CE(s0,s4) CE(s0,s6) CE(s1,s6) CE(s3,s6) CE(s5,s6) }

__global__ __launch_bounds__(256, 2) void mega_k(const float4* __restrict__ in,
                                                 float4* __restrict__ out,
                                                 float w0, float w1, float w2) {
    __shared__ float4 A_[RB][40];   // 32000 B ; float col of f4 idx ca: 4*ca-16 (rel to x0)
    __shared__ float4 B_[RB][38];   // 30400 B ; float col of f4 idx cbi: 4*cbi-12
    int b  = blockIdx.x;
    int sw = (b & 7) * 300 + (b >> 3);       // 2400 = 8*300 XCD chunk swizzle
    int tx = sw % 10; int t2 = sw / 10;
    int ty = t2 % 15; int n  = t2 / 15;
    int x0 = tx * 128, y0 = ty * 24;
    int tid = threadIdx.x;
    const long ib = (long)n * (IH * W4);
    const int xb4 = x0 >> 2;

    // ---------------- P0: load + invert; OOB -> -FLT_MAX ----------------
    for (int i = tid; i < 50 * 40; i += 256) {
        int ra = i / 40, ca = i % 40;
        int gy = y0 + ra - 13, gx4 = xb4 + ca - 4;
        float4 v;
        if ((unsigned)gy < IH && (unsigned)gx4 < W4) {
            v = in[ib + gy * W4 + gx4];
            v.x = v.x > MIND ? MAXD - v.x : v.x;
            v.y = v.y > MIND ? MAXD - v.y : v.y;
            v.z = v.z > MIND ? MAXD - v.z : v.z;
            v.w = v.w > MIND ? MAXD - v.w : v.w;
        } else { v.x = v.y = v.z = v.w = -FLT_MAX; }
        A_[ra][ca] = v;
    }
    __syncthreads();

    // ---------------- P1: h-dilate9 (A -> B), rows 0..49, cb 0..37 ----------------
    for (int i = tid; i < 50 * 38; i += 256) {
        int ra = i / 38, cb = i % 38;
        float t[12];
        *(float4*)&t[0] = A_[ra][cb];
        *(float4*)&t[4] = A_[ra][cb + 1];
        *(float4*)&t[8] = A_[ra][cb + 2];
        float core = fmaxf(fmaxf(fmaxf(t[3],t[4]), fmaxf(t[5],t[6])), fmaxf(t[7],t[8]));
        float a12 = fmaxf(t[1], t[2]), a910 = fmaxf(t[9], t[10]);
        float4 o;
        o.x = fmaxf(fmaxf(core, a12), t[0]);
        o.y = fmaxf(fmaxf(core, a12), t[9]);
        o.z = fmaxf(fmaxf(core, t[2]), a910);
        o.w = fmaxf(fmaxf(core, a910), t[11]);
        B_[ra][cb] = o;
    }
    __syncthreads();

    // ---------------- P2: v-dilate9 (B -> A), ra 4..45, 38 cols x 6 runs of 7 ----------------
    {
        int c = tid % 38, k = tid / 38;
        if (k < 6) {
            int ra0 = 4 + 7 * k;
            float4 w[9];
            #pragma unroll
            for (int j = 0; j < 8; ++j) w[j] = B_[ra0 - 4 + j][c];
            #pragma unroll
            for (int s = 0; s < 7; ++s) {
                w[8] = B_[ra0 + 4 + s][c];
                float4 m = w[0];
                #pragma unroll
                for (int j = 1; j < 9; ++j) m = vmax4(m, w[j]);
                A_[ra0 + s][c + 1] = m;
                #pragma unroll
                for (int j = 0; j < 8; ++j) w[j] = w[j + 1];
            }
        }
    }
    __syncthreads();

    // ---------------- P3: h-erode5 (A -> B), ra 4..45, cb 0..35; OOB read -> +FLT_MAX ------
    for (int i = tid; i < 42 * 36; i += 256) {
        int ra = i / 36 + 4, cb = i % 36;
        float t[12];
        *(float4*)&t[0] = A_[ra][cb + 1];
        *(float4*)&t[4] = A_[ra][cb + 2];
        *(float4*)&t[8] = A_[ra][cb + 3];
        bool rOK = (unsigned)(y0 + ra - 13) < IH;
        #pragma unroll
        for (int kk = 2; kk <= 9; ++kk) {
            int gx = x0 + 4 * cb - 12 + kk;
            t[kk] = (rOK && (unsigned)gx < IW) ? t[kk] : FLT_MAX;
        }
        float m34 = fminf(t[3], t[4]), m56 = fminf(t[5], t[6]), m78 = fminf(t[7], t[8]);
        float4 o;
        o.x = fminf(fminf(t[2], m34), m56);
        o.y = fminf(fminf(m34, m56), t[7]);
        o.z = fminf(fminf(t[4], m56), m78);
        o.w = fminf(fminf(m56, m78), t[9]);
        B_[ra][cb + 1] = o;
    }
    __syncthreads();

    // ---------------- P4: v-erode5 (B -> A), ra 6..43, 36 cols x 7 runs of <=6 --------------
    {
        int c = tid % 36, k = tid / 36;
        if (k < 7) {
            int ra0 = 6 + 6 * k;
            int rlen = min(6, 44 - ra0);
            float4 w[5];
            #pragma unroll
            for (int j = 0; j < 4; ++j) w[j] = B_[ra0 - 2 + j][c + 1];
            #pragma unroll
            for (int s = 0; s < 6; ++s) {
                if (s < rlen) {
                    w[4] = B_[ra0 + 2 + s][c + 1];
                    float4 m = w[0];
                    #pragma unroll
                    for (int j = 1; j < 5; ++j) m = vmin4(m, w[j]);
                    A_[ra0 + s][c + 2] = m;
                    #pragma unroll
                    for (int j = 0; j < 4; ++j) w[j] = w[j + 1];
                }
            }
        }
    }
    __syncthreads();

    // ---------------- P5: h-dilate7 (A -> B), ra 6..43, cb2 0..33; OOB -> -FLT_MAX ---------
    for (int i = tid; i < 38 * 34; i += 256) {
        int ra = i / 34 + 6, cb2 = i % 34;
        float t[12];
        *(float4*)&t[0] = A_[ra][cb2 + 2];
        *(float4*)&t[4] = A_[ra][cb2 + 3];
        *(float4*)&t[8] = A_[ra][cb2 + 4];
        bool rOK = (unsigned)(y0 + ra - 13) < IH;
        #pragma unroll
        for (int kk = 1; kk <= 10; ++kk) {
            int gx = x0 + 4 * cb2 - 8 + kk;
            t[kk] = (rOK && (unsigned)gx < IW) ? t[kk] : -FLT_MAX;
        }
        float core = fmaxf(fmaxf(t[4], t[5]), fmaxf(t[6], t[7]));
        float a23 = fmaxf(t[2], t[3]), a89 = fmaxf(t[8], t[9]);
        float4 o;
        o.x = fmaxf(fmaxf(core, a23), t[1]);
        o.y = fmaxf(fmaxf(core, a23), t[8]);
        o.z = fmaxf(fmaxf(core, t[3]), a89);
        o.w = fmaxf(fmaxf(core, a89), t[10]);
        B_[ra][cb2 + 2] = o;
    }
    __syncthreads();

    // ---------------- P6: v-dilate7 + fill (B,A -> A), ra 9..40, 34 cols x 7 runs of <=5 ----
    {
        int c = tid % 34, k = tid / 34;
        if (k < 7) {
            int ra0 = 9 + 5 * k;
            int rlen = min(5, 41 - ra0);
            float4 w[7];
            #pragma unroll
            for (int j = 0; j < 6; ++j) w[j] = B_[ra0 - 3 + j][c + 2];
            #pragma unroll
            for (int s = 0; s < 5; ++s) {
                if (s < rlen) {
                    w[6] = B_[ra0 + 3 + s][c + 2];
                    float4 m = w[0];
                    #pragma unroll
                    for (int j = 1; j < 7; ++j) m = vmax4(m, w[j]);
                    float4 cl = A_[ra0 + s][c + 3];
                    float4 o;
                    o.x = cl.x < MIND ? m.x : cl.x;
                    o.y = cl.y < MIND ? m.y : cl.y;
                    o.z = cl.z < MIND ? m.z : cl.z;
                    o.w = cl.w < MIND ? m.w : cl.w;
                    A_[ra0 + s][c + 3] = o;
                    #pragma unroll
                    for (int j = 0; j < 6; ++j) w[j] = w[j + 1];
                }
            }
        }
    }
    __syncthreads();

    // ---------------- P7: 5x5 median (A -> B), ra 11..38, 34 cols x 7 runs of 4 ------------
    {
        int c = tid % 34, k = tid / 34;
        if (k < 7) {
            int ra0 = 11 + 4 * k;
            float rows_[5][8];
            auto loadrow = [&](float* rw, int rr) {
                float4 q0 = A_[rr][c + 2], q1 = A_[rr][c + 3], q2 = A_[rr][c + 4];
                float tmp[8] = {q0.z, q0.w, q1.x, q1.y, q1.z, q1.w, q2.x, q2.y};
                bool rOK = (unsigned)(y0 + rr - 13) < IH;
                #pragma unroll
                for (int j = 0; j < 8; ++j) {
                    int gx = x0 + 4 * c - 6 + j;
                    rw[j] = (rOK && (unsigned)gx < IW) ? tmp[j] : 0.0f;
                }
            };
            #pragma unroll
            for (int j = 0; j < 4; ++j) loadrow(rows_[j], ra0 - 2 + j);
            #pragma unroll
            for (int st = 0; st < 4; ++st) {
                loadrow(rows_[4], ra0 + 2 + st);
                float cs[8][5];
                #pragma unroll
                for (int j = 0; j < 8; ++j) {
                    float a0 = rows_[0][j], a1 = rows_[1][j], a2 = rows_[2][j],
                          a3 = rows_[3][j], a4 = rows_[4][j];
                    SORT5(a0, a1, a2, a3, a4)
                    cs[j][0] = a0; cs[j][1] = a1; cs[j][2] = a2; cs[j][3] = a3; cs[j][4] = a4;
                }
                float rr4[4];
                #pragma unroll
                for (int p = 0; p < 4; ++p) {
                    float m[5][5];
                    #pragma unroll
                    for (int i2 = 0; i2 < 5; ++i2) {
                        m[i2][0] = cs[p][i2];     m[i2][1] = cs[p + 1][i2];
                        m[i2][2] = cs[p + 2][i2]; m[i2][3] = cs[p + 3][i2];
                        m[i2][4] = cs[p + 4][i2];
                        SORT5(m[i2][0], m[i2][1], m[i2][2], m[i2][3], m[i2][4])
                    }
                    float s0 = m[0][3], s1 = m[0][4], s2 = m[1][2], s3 = m[1][3];
                    float s4 = m[1][4], s5 = m[2][1], s6 = m[2][2], s7 = m[2][3];
                    MM8(s0, s1, s2, s3, s4, s5, s6, s7)
                    s0 = m[3][0]; s7 = m[3][1];
                    MM8(s0, s1, s2, s3, s4, s5, s6, s7)
                    s0 = m[3][2]; s7 = m[4][0];
                    MM8(s0, s1, s2, s3, s4, s5, s6, s7)
                    s0 = m[4][1];
                    MM7(s0, s1, s2, s3, s4, s5, s6)
                    CE(s1, s2) CE(s3, s4) CE(s1, s3) CE(s2, s4)
                    float mn = fminf(s2, s3), mx = fmaxf(s2, s3);
                    rr4[p] = fmaxf(mn, fminf(mx, s5));
                }
                B_[ra0 + st][c + 2] = make_float4(rr4[0], rr4[1], rr4[2], rr4[3]);
                #pragma unroll
                for (int j = 0; j < 4; ++j) {
                    #pragma unroll
                    for (int q = 0; q < 8; ++q) rows_[j][q] = rows_[j + 1][q];
                }
            }
        }
    }
    __syncthreads();

    // ---------------- P8: h-gauss reflect (B -> A), ra 11..38, cb3 0..31 --------------------
    for (int i = tid; i < 28 * 32; i += 256) {
        int ra = i / 32 + 11, cb3 = i % 32;
        float t[12];
        *(float4*)&t[0] = B_[ra][cb3 + 2];
        *(float4*)&t[4] = B_[ra][cb3 + 3];
        *(float4*)&t[8] = B_[ra][cb3 + 4];
        if (x0 == 0 && cb3 == 0)      { t[2] = t[6]; t[3] = t[5]; }   // cols -2,-1 -> 2,1
        if (x0 == 1152 && cb3 == 15)  { t[8] = t[6]; t[9] = t[5]; }   // cols 1216,1217 -> 1214,1213
        float4 o;
        o.x = w2 * (t[2] + t[6]) + w1 * (t[3] + t[5]) + w0 * t[4];
        o.y = w2 * (t[3] + t[7]) + w1 * (t[4] + t[6]) + w0 * t[5];
        o.z = w2 * (t[4] + t[8]) + w1 * (t[5] + t[7]) + w0 * t[6];
        o.w = w2 * (t[5] + t[9]) + w1 * (t[6] + t[8]) + w0 * t[7];
        A_[ra][cb3 + 4] = o;
    }
    __syncthreads();

    // ---------------- P9: v-gauss reflect + select + invert + store, 32 cols x 8 runs of 3 --
    {
        int c = tid % 32, k = tid / 32;
        int ra0 = 13 + 3 * k;
        #pragma unroll
        for (int s = 0; s < 3; ++s) {
            int ra = ra0 + s;
            int gy = y0 + ra - 13;
            float4 acc = make_float4(0.f, 0.f, 0.f, 0.f);
            #pragma unroll
            for (int d = -2; d <= 2; ++d) {
                int gy2 = gy + d;
                gy2 = gy2 < 0 ? -gy2 : gy2;
                gy2 = gy2 >= IH ? 2 * IH - 2 - gy2 : gy2;
                int ra2 = gy2 - y0 + 13;
                float4 hv = A_[ra2][c + 4];
                float wd = (d == 0) ? w0 : ((d == 1 || d == -1) ? w1 : w2);
                acc.x = fmaf(wd, hv.x, acc.x); acc.y = fmaf(wd, hv.y, acc.y);
                acc.z = fmaf(wd, hv.z, acc.z); acc.w = fmaf(wd, hv.w, acc.w);
            }
            float4 dm = B_[ra][c + 3];
            float4 o;
            { float sv = dm.x > MIND ? acc.x : dm.x; o.x = sv > MIND ? MAXD - sv : sv; }
            { float sv = dm.y > MIND ? acc.y : dm.y; o.y = sv > MIND ? MAXD - sv : sv; }
            { float sv = dm.z > MIND ? acc.z : dm.z; o.z = sv > MIND ? MAXD - sv : sv; }
            { float sv = dm.w > MIND ? acc.w : dm.w; o.w = sv > MIND ? MAXD - sv : sv; }
            int gx4 = xb4 + c;
            if (gy < IH && gx4 < W4) out[ib + (long)gy * W4 + gx4] = o;
        }
    }
}

extern "C" void kernel_launch(void* const* d_in, const int* in_sizes, int n_in,
                              void* d_out, int out_size, void* d_ws, size_t ws_size,
                              hipStream_t stream) {
    const float4* in = (const float4*)d_in[0];
    float4* O = (float4*)d_out;

    // Gaussian weights: sigma = 1.1 -> 2*sigma^2 = 2.42
    float c2 = 2.42f;
    float e1 = expf(-1.0f / c2);
    float e4 = expf(-4.0f / c2);
    float s  = 1.0f + 2.0f * e1 + 2.0f * e4;
    float w0 = 1.0f / s, w1 = e1 / s, w2 = e4 / s;

    mega_k<<<dim3(2400), dim3(256), 0, stream>>>(in, O, w0, w1, w2);
}

// Round 4
// 176.822 us; speedup vs baseline: 1.9842x; 1.0308x over previous
//
#include <hip/hip_runtime.h>
#include <float.h>
#include <math.h>

#define IW 1216
#define IH 352
#define W4 304
#define MIND 0.1f
#define MAXD 100.0f
// tile: 128 wide x 16 tall output; buffer rows rel -13..28 (ra = rel+13) -> 42 rows
#define RB 42

__device__ __forceinline__ float4 vmax4(float4 a, float4 b) {
    return make_float4(fmaxf(a.x,b.x), fmaxf(a.y,b.y), fmaxf(a.z,b.z), fmaxf(a.w,b.w));
}
__device__ __forceinline__ float4 vmin4(float4 a, float4 b) {
    return make_float4(fminf(a.x,b.x), fminf(a.y,b.y), fminf(a.z,b.z), fminf(a.w,b.w));
}

#define CE(a,b) { float _l = fminf(a,b), _h = fmaxf(a,b); a = _l; b = _h; }
#define SORT5(a,b,c,d,e) { CE(a,b) CE(d,e) CE(c,e) CE(c,d) CE(a,d) CE(a,c) CE(b,e) CE(b,d) CE(b,c) }
#define MM8(s0,s1,s2,s3,s4,s5,s6,s7) { CE(s0,s1) CE(s2,s3) CE(s4,s5) CE(s6,s7) \
    CE(s0,s2) CE(s0,s4) CE(s0,s6) CE(s1,s7) CE(s3,s7) CE(s5,s7) }
#define MM7(s0,s1,s2,s3,s4,s5,s6) { CE(s0,s1) CE(s2,s3) CE(s4,s5) \
    CE(s0,s2) CE(s0,s4) CE(s0,s6) CE(s1,s6) CE(s3,s6) CE(s5,s6) }

__global__ __launch_bounds__(256, 3) void mega_k(const float4* __restrict__ in,
                                                 float4* __restrict__ out,
                                                 float w0, float w1, float w2) {
    __shared__ float4 A_[RB][41];   // +1 f4 pad: row stride 164 words == 4 mod 32
    __shared__ float4 B_[RB][39];   // +1 f4 pad: row stride 156 words == 28 mod 32
    int b  = blockIdx.x;
    int sw = (b & 7) * 440 + (b >> 3);       // 3520 = 8*440 XCD chunk swizzle
    int tx = sw % 10; int t2 = sw / 10;
    int ty = t2 % 22; int n  = t2 / 22;
    int x0 = tx * 128, y0 = ty * 16;
    int tid = threadIdx.x;
    const long ib = (long)n * (IH * W4);
    const int xb4 = x0 >> 2;
    const bool interior = (tx >= 1) && (tx <= 8) && (ty >= 1) && (ty <= 20);

    // ---------------- P0: load + invert; OOB -> -FLT_MAX ----------------
    if (interior) {
        for (int i = tid; i < RB * 40; i += 256) {
            int ra = i / 40, ca = i % 40;
            int gy = y0 + ra - 13, gx4 = xb4 + ca - 4;
            float4 v = in[ib + gy * W4 + gx4];
            v.x = v.x > MIND ? MAXD - v.x : v.x;
            v.y = v.y > MIND ? MAXD - v.y : v.y;
            v.z = v.z > MIND ? MAXD - v.z : v.z;
            v.w = v.w > MIND ? MAXD - v.w : v.w;
            A_[ra][ca] = v;
        }
    } else {
        for (int i = tid; i < RB * 40; i += 256) {
            int ra = i / 40, ca = i % 40;
            int gy = y0 + ra - 13, gx4 = xb4 + ca - 4;
            float4 v;
            if ((unsigned)gy < IH && (unsigned)gx4 < W4) {
                v = in[ib + gy * W4 + gx4];
                v.x = v.x > MIND ? MAXD - v.x : v.x;
                v.y = v.y > MIND ? MAXD - v.y : v.y;
                v.z = v.z > MIND ? MAXD - v.z : v.z;
                v.w = v.w > MIND ? MAXD - v.w : v.w;
            } else { v.x = v.y = v.z = v.w = -FLT_MAX; }
            A_[ra][ca] = v;
        }
    }
    __syncthreads();

    // ---------------- P1: h-dilate9 (A -> B), rows 0..41, cb 0..37 ----------------
    for (int i = tid; i < RB * 38; i += 256) {
        int ra = i / 38, cb = i % 38;
        float t[12];
        *(float4*)&t[0] = A_[ra][cb];
        *(float4*)&t[4] = A_[ra][cb + 1];
        *(float4*)&t[8] = A_[ra][cb + 2];
        float core = fmaxf(fmaxf(fmaxf(t[3],t[4]), fmaxf(t[5],t[6])), fmaxf(t[7],t[8]));
        float a12 = fmaxf(t[1], t[2]), a910 = fmaxf(t[9], t[10]);
        float4 o;
        o.x = fmaxf(fmaxf(core, a12), t[0]);
        o.y = fmaxf(fmaxf(core, a12), t[9]);
        o.z = fmaxf(fmaxf(core, t[2]), a910);
        o.w = fmaxf(fmaxf(core, a910), t[11]);
        B_[ra][cb] = o;
    }
    __syncthreads();

    // ---------------- P2: v-dilate9 (B -> A), ra 4..37, 38 cols x 6 runs of <=6 -------------
    {
        int c = tid % 38, k = tid / 38;
        if (k < 6) {
            int ra0 = 4 + 6 * k;
            float4 w[9];
            #pragma unroll
            for (int j = 0; j < 8; ++j) w[j] = B_[ra0 - 4 + j][c];
            #pragma unroll
            for (int s = 0; s < 6; ++s) {
                if (ra0 + s <= 37) {
                    w[8] = B_[ra0 + 4 + s][c];
                    float4 m = w[0];
                    #pragma unroll
                    for (int j = 1; j < 9; ++j) m = vmax4(m, w[j]);
                    A_[ra0 + s][c + 1] = m;
                    #pragma unroll
                    for (int j = 0; j < 8; ++j) w[j] = w[j + 1];
                }
            }
        }
    }
    __syncthreads();

    // ---------------- P3: h-erode5 (A -> B), ra 4..37, cb 0..35; OOB read -> +FLT_MAX ------
    for (int i = tid; i < 34 * 36; i += 256) {
        int ra = i / 36 + 4, cb = i % 36;
        float t[12];
        *(float4*)&t[0] = A_[ra][cb + 1];
        *(float4*)&t[4] = A_[ra][cb + 2];
        *(float4*)&t[8] = A_[ra][cb + 3];
        if (!interior) {
            bool rOK = (unsigned)(y0 + ra - 13) < IH;
            #pragma unroll
            for (int kk = 2; kk <= 9; ++kk) {
                int gx = x0 + 4 * cb - 12 + kk;
                t[kk] = (rOK && (unsigned)gx < IW) ? t[kk] : FLT_MAX;
            }
        }
        float m34 = fminf(t[3], t[4]), m56 = fminf(t[5], t[6]), m78 = fminf(t[7], t[8]);
        float4 o;
        o.x = fminf(fminf(t[2], m34), m56);
        o.y = fminf(fminf(m34, m56), t[7]);
        o.z = fminf(fminf(t[4], m56), m78);
        o.w = fminf(fminf(m56, m78), t[9]);
        B_[ra][cb + 1] = o;
    }
    __syncthreads();

    // ---------------- P4: v-erode5 (B -> A), ra 6..35, 36 cols x 6 runs of 5 ----------------
    {
        int c = tid % 36, k = tid / 36;
        if (k < 6) {
            int ra0 = 6 + 5 * k;
            float4 w[5];
            #pragma unroll
            for (int j = 0; j < 4; ++j) w[j] = B_[ra0 - 2 + j][c + 1];
            #pragma unroll
            for (int s = 0; s < 5; ++s) {
                w[4] = B_[ra0 + 2 + s][c + 1];
                float4 m = w[0];
                #pragma unroll
                for (int j = 1; j < 5; ++j) m = vmin4(m, w[j]);
                A_[ra0 + s][c + 2] = m;
                #pragma unroll
                for (int j = 0; j < 4; ++j) w[j] = w[j + 1];
            }
        }
    }
    __syncthreads();

    // ---------------- P5: h-dilate7 (A -> B), ra 6..35, cb2 0..33; OOB -> -FLT_MAX ---------
    for (int i = tid; i < 30 * 34; i += 256) {
        int ra = i / 34 + 6, cb2 = i % 34;
        float t[12];
        *(float4*)&t[0] = A_[ra][cb2 + 2];
        *(float4*)&t[4] = A_[ra][cb2 + 3];
        *(float4*)&t[8] = A_[ra][cb2 + 4];
        if (!interior) {
            bool rOK = (unsigned)(y0 + ra - 13) < IH;
            #pragma unroll
            for (int kk = 1; kk <= 10; ++kk) {
                int gx = x0 + 4 * cb2 - 8 + kk;
                t[kk] = (rOK && (unsigned)gx < IW) ? t[kk] : -FLT_MAX;
            }
        }
        float core = fmaxf(fmaxf(t[4], t[5]), fmaxf(t[6], t[7]));
        float a23 = fmaxf(t[2], t[3]), a89 = fmaxf(t[8], t[9]);
        float4 o;
        o.x = fmaxf(fmaxf(core, a23), t[1]);
        o.y = fmaxf(fmaxf(core, a23), t[8]);
        o.z = fmaxf(fmaxf(core, t[3]), a89);
        o.w = fmaxf(fmaxf(core, a89), t[10]);
        B_[ra][cb2 + 2] = o;
    }
    __syncthreads();

    // ---------------- P6: v-dilate7 + fill (B,A -> A), ra 9..32, 34 cols x 6 runs of 4 ------
    {
        int c = tid % 34, k = tid / 34;
        if (k < 6) {
            int ra0 = 9 + 4 * k;
            float4 w[7];
            #pragma unroll
            for (int j = 0; j < 6; ++j) w[j] = B_[ra0 - 3 + j][c + 2];
            #pragma unroll
            for (int s = 0; s < 4; ++s) {
                w[6] = B_[ra0 + 3 + s][c + 2];
                float4 m = w[0];
                #pragma unroll
                for (int j = 1; j < 7; ++j) m = vmax4(m, w[j]);
                float4 cl = A_[ra0 + s][c + 3];
                float4 o;
                o.x = cl.x < MIND ? m.x : cl.x;
                o.y = cl.y < MIND ? m.y : cl.y;
                o.z = cl.z < MIND ? m.z : cl.z;
                o.w = cl.w < MIND ? m.w : cl.w;
                A_[ra0 + s][c + 3] = o;
                #pragma unroll
                for (int j = 0; j < 6; ++j) w[j] = w[j + 1];
            }
        }
    }
    __syncthreads();

    // ---------------- P7: 5x5 median (A -> B), ra 11..30, 34 cols x 7 runs of <=3 -----------
    {
        int c = tid % 34, k = tid / 34;
        if (k < 7) {
            int ra0 = 11 + 3 * k;
            int rlen = min(3, 31 - ra0);
            float rows_[5][8];
            auto loadrow = [&](float* rw, int rr) {
                float4 q0 = A_[rr][c + 2], q1 = A_[rr][c + 3], q2 = A_[rr][c + 4];
                float tmp[8] = {q0.z, q0.w, q1.x, q1.y, q1.z, q1.w, q2.x, q2.y};
                if (interior) {
                    #pragma unroll
                    for (int j = 0; j < 8; ++j) rw[j] = tmp[j];
                } else {
                    bool rOK = (unsigned)(y0 + rr - 13) < IH;
                    #pragma unroll
                    for (int j = 0; j < 8; ++j) {
                        int gx = x0 + 4 * c - 6 + j;
                        rw[j] = (rOK && (unsigned)gx < IW) ? tmp[j] : 0.0f;
                    }
                }
            };
            #pragma unroll
            for (int j = 0; j < 4; ++j) loadrow(rows_[j], ra0 - 2 + j);
            #pragma unroll
            for (int st = 0; st < 3; ++st) {
                if (st < rlen) {
                    loadrow(rows_[4], ra0 + 2 + st);
                    float cs[8][5];
                    #pragma unroll
                    for (int j = 0; j < 8; ++j) {
                        float a0 = rows_[0][j], a1 = rows_[1][j], a2 = rows_[2][j],
                              a3 = rows_[3][j], a4 = rows_[4][j];
                        SORT5(a0, a1, a2, a3, a4)
                        cs[j][0] = a0; cs[j][1] = a1; cs[j][2] = a2; cs[j][3] = a3; cs[j][4] = a4;
                    }
                    float rr4[4];
                    #pragma unroll
                    for (int p = 0; p < 4; ++p) {
                        float m[5][5];
                        #pragma unroll
                        for (int i2 = 0; i2 < 5; ++i2) {
                            m[i2][0] = cs[p][i2];     m[i2][1] = cs[p + 1][i2];
                            m[i2][2] = cs[p + 2][i2]; m[i2][3] = cs[p + 3][i2];
                            m[i2][4] = cs[p + 4][i2];
                            SORT5(m[i2][0], m[i2][1], m[i2][2], m[i2][3], m[i2][4])
                        }
                        float s0 = m[0][3], s1 = m[0][4], s2 = m[1][2], s3 = m[1][3];
                        float s4 = m[1][4], s5 = m[2][1], s6 = m[2][2], s7 = m[2][3];
                        MM8(s0, s1, s2, s3, s4, s5, s6, s7)
                        s0 = m[3][0]; s7 = m[3][1];
                        MM8(s0, s1, s2, s3, s4, s5, s6, s7)
                        s0 = m[3][2]; s7 = m[4][0];
                        MM8(s0, s1, s2, s3, s4, s5, s6, s7)
                        s0 = m[4][1];
                        MM7(s0, s1, s2, s3, s4, s5, s6)
                        CE(s1, s2) CE(s3, s4) CE(s1, s3) CE(s2, s4)
                        float mn = fminf(s2, s3), mx = fmaxf(s2, s3);
                        rr4[p] = fmaxf(mn, fminf(mx, s5));
                    }
                    B_[ra0 + st][c + 2] = make_float4(rr4[0], rr4[1], rr4[2], rr4[3]);
                    #pragma unroll
                    for (int j = 0; j < 4; ++j) {
                        #pragma unroll
                        for (int q = 0; q < 8; ++q) rows_[j][q] = rows_[j + 1][q];
                    }
                }
            }
        }
    }
    __syncthreads();

    // ---------------- P8: h-gauss reflect (B -> A), ra 11..30, cb3 0..31 --------------------
    for (int i = tid; i < 20 * 32; i += 256) {
        int ra = i / 32 + 11, cb3 = i % 32;
        float t[12];
        *(float4*)&t[0] = B_[ra][cb3 + 2];
        *(float4*)&t[4] = B_[ra][cb3 + 3];
        *(float4*)&t[8] = B_[ra][cb3 + 4];
        if (x0 == 0 && cb3 == 0)      { t[2] = t[6]; t[3] = t[5]; }   // cols -2,-1 -> 2,1
        if (x0 == 1152 && cb3 == 15)  { t[8] = t[6]; t[9] = t[5]; }   // cols 1216,1217 -> 1214,1213
        float4 o;
        o.x = w2 * (t[2] + t[6]) + w1 * (t[3] + t[5]) + w0 * t[4];
        o.y = w2 * (t[3] + t[7]) + w1 * (t[4] + t[6]) + w0 * t[5];
        o.z = w2 * (t[4] + t[8]) + w1 * (t[5] + t[7]) + w0 * t[6];
        o.w = w2 * (t[5] + t[9]) + w1 * (t[6] + t[8]) + w0 * t[7];
        A_[ra][cb3 + 4] = o;
    }
    __syncthreads();

    // ---------------- P9: v-gauss reflect + select + invert + store, 32 cols x 8 runs of 2 --
    {
        int c = tid % 32, k = tid / 32;
        int ra0 = 13 + 2 * k;
        #pragma unroll
        for (int s = 0; s < 2; ++s) {
            int ra = ra0 + s;
            int gy = y0 + ra - 13;                 // always in [0, IH)
            float4 acc = make_float4(0.f, 0.f, 0.f, 0.f);
            #pragma unroll
            for (int d = -2; d <= 2; ++d) {
                int gy2 = gy + d;
                gy2 = gy2 < 0 ? -gy2 : gy2;
                gy2 = gy2 >= IH ? 2 * IH - 2 - gy2 : gy2;
                int ra2 = gy2 - y0 + 13;
                float4 hv = A_[ra2][c + 4];
                float wd = (d == 0) ? w0 : ((d == 1 || d == -1) ? w1 : w2);
                acc.x = fmaf(wd, hv.x, acc.x); acc.y = fmaf(wd, hv.y, acc.y);
                acc.z = fmaf(wd, hv.z, acc.z); acc.w = fmaf(wd, hv.w, acc.w);
            }
            float4 dm = B_[ra][c + 3];
            float4 o;
            { float sv = dm.x > MIND ? acc.x : dm.x; o.x = sv > MIND ? MAXD - sv : sv; }
            { float sv = dm.y > MIND ? acc.y : dm.y; o.y = sv > MIND ? MAXD - sv : sv; }
            { float sv = dm.z > MIND ? acc.z : dm.z; o.z = sv > MIND ? MAXD - sv : sv; }
            { float sv = dm.w > MIND ? acc.w : dm.w; o.w = sv > MIND ? MAXD - sv : sv; }
            int gx4 = xb4 + c;
            if (gx4 < W4) out[ib + (long)gy * W4 + gx4] = o;
        }
    }
}

extern "C" void kernel_launch(void* const* d_in, const int* in_sizes, int n_in,
                              void* d_out, int out_size, void* d_ws, size_t ws_size,
                              hipStream_t stream) {
    const float4* in = (const float4*)d_in[0];
    float4* O = (float4*)d_out;

    // Gaussian weights: sigma = 1.1 -> 2*sigma^2 = 2.42
    float c2 = 2.42f;
    float e1 = expf(-1.0f / c2);
    float e4 = expf(-4.0f / c2);
    float s  = 1.0f + 2.0f * e1 + 2.0f * e4;
    float w0 = 1.0f / s, w1 = e1 / s, w2 = e4 / s;

    mega_k<<<dim3(3520), dim3(256), 0, stream>>>(in, O, w0, w1, w2);
}

// Round 7
// 172.291 us; speedup vs baseline: 2.0364x; 1.0263x over previous
//
#include <hip/hip_runtime.h>
#include <float.h>
#include <math.h>

#define IW 1216
#define IH 352
#define W4 304
#define MIND 0.1f
#define MAXD 100.0f
// tile: 128 wide x 16 tall output; single LDS buffer rows rel -13..28 (ra = rel+13)
// S col c <-> global f4 (xb4 + c - 3) <-> px (4c-12 .. 4c-9) relative to x0
#define RB 42
#define SWD 39

__device__ __forceinline__ float4 vmax4(float4 a, float4 b) {
    return make_float4(fmaxf(a.x,b.x), fmaxf(a.y,b.y), fmaxf(a.z,b.z), fmaxf(a.w,b.w));
}
__device__ __forceinline__ float4 vmin4(float4 a, float4 b) {
    return make_float4(fminf(a.x,b.x), fminf(a.y,b.y), fminf(a.z,b.z), fminf(a.w,b.w));
}

#define CE(a,b) { float _l = fminf(a,b), _h = fmaxf(a,b); a = _l; b = _h; }
#define FE(a,b) { float _h = fmaxf(a,b), _l = fminf(a,b); a = _h; b = _l; }
#define SORT5(a,b,c,d,e) { CE(a,b) CE(d,e) CE(c,e) CE(c,d) CE(a,d) CE(a,c) CE(b,e) CE(b,d) CE(b,c) }
#define MM8(s0,s1,s2,s3,s4,s5,s6,s7) { CE(s0,s1) CE(s2,s3) CE(s4,s5) CE(s6,s7) \
    CE(s0,s2) CE(s0,s4) CE(s0,s6) CE(s1,s7) CE(s3,s7) CE(s5,s7) }
#define MM7(s0,s1,s2,s3,s4,s5,s6) { CE(s0,s1) CE(s2,s3) CE(s4,s5) \
    CE(s0,s2) CE(s0,s4) CE(s0,s6) CE(s1,s6) CE(s3,s6) CE(s5,s6) }

// ---- partial order-statistic networks (0-1 verified; outputs are value-SETS) ----
__device__ __forceinline__ void top2_5(float a, float b, float c, float d, float e,
                                       float& o1, float& o2) {
    float mab = fmaxf(a,b), nab = fminf(a,b);
    float mcd = fmaxf(c,d), ncd = fminf(c,d);
    float hi4 = fmaxf(mab, mcd);
    float lo2 = fmaxf(fminf(mab, mcd), fmaxf(nab, ncd));
    o2 = fmaxf(hi4, e);
    o1 = fmaxf(fminf(hi4, e), lo2);
}
__device__ __forceinline__ void bot2_5(float a, float b, float c, float d, float e,
                                       float& o1, float& o2) {
    float mab = fmaxf(a,b), nab = fminf(a,b);
    float mcd = fmaxf(c,d), ncd = fminf(c,d);
    float lo4 = fminf(nab, ncd);
    float hi2 = fminf(fmaxf(nab, ncd), fminf(mab, mcd));
    o2 = fminf(lo4, e);
    o1 = fminf(fmaxf(lo4, e), hi2);
}
__device__ __forceinline__ void top3_5(float a, float b, float c, float d, float e,
                                       float& o1, float& o2, float& o3) {
    CE(a,b) CE(c,d) CE(a,c) CE(b,d) CE(a,e) CE(b,c) CE(b,e)
    o1 = c; o2 = d; o3 = e;
}
__device__ __forceinline__ void bot3_5(float a, float b, float c, float d, float e,
                                       float& o1, float& o2, float& o3) {
    FE(a,b) FE(c,d) FE(a,c) FE(b,d) FE(a,e) FE(b,c) FE(b,e)
    o1 = c; o2 = d; o3 = e;
}
__device__ __forceinline__ void mid3_5(float a, float b, float c, float d, float e,
                                       float& o1, float& o2, float& o3) {
    CE(a,b) CE(c,d) CE(a,c) CE(b,d) CE(a,e) CE(d,e)
    o1 = b; o2 = c; o3 = d;
}

__global__ __launch_bounds__(256, 4) void mega_k(const float4* __restrict__ in,
                                                 float4* __restrict__ out,
                                                 float w0, float w1, float w2) {
    __shared__ float4 S[RB][SWD];   // 26208 B
    int b  = blockIdx.x;
    int sw = (b & 7) * 440 + (b >> 3);       // 3520 = 8*440 XCD chunk swizzle
    int tx = sw % 10; int t2 = sw / 10;
    int ty = t2 % 22; int n  = t2 / 22;
    int x0 = tx * 128, y0 = ty * 16;
    int tid = threadIdx.x;
    const long ib = (long)n * (IH * W4);
    const int xb4 = x0 >> 2;
    const bool interior = (tx >= 1) && (tx <= 8) && (ty >= 1) && (ty <= 20);

    // ---------------- P01: global load + invert + h-dilate9 -> S rows 0..41, cols 0..37 -----
    {
        int j = tid % 6, r = tid / 6;
        if (r < RB) {
            int c0 = 7 * j;
            int nc = (j == 5) ? 3 : 7;
            int gy = y0 + r - 13;
            bool rok = (unsigned)gy < IH;
            float4 lf[9];
            #pragma unroll
            for (int q = 0; q < 9; ++q) {
                if (q < nc + 2) {
                    int g = xb4 + c0 - 4 + q;
                    float4 v;
                    if (rok && (unsigned)g < W4) {
                        v = in[ib + gy * W4 + g];
                        v.x = v.x > MIND ? MAXD - v.x : v.x;
                        v.y = v.y > MIND ? MAXD - v.y : v.y;
                        v.z = v.z > MIND ? MAXD - v.z : v.z;
                        v.w = v.w > MIND ? MAXD - v.w : v.w;
                    } else { v.x = v.y = v.z = v.w = -FLT_MAX; }
                    lf[q] = v;
                }
            }
            #pragma unroll
            for (int s = 0; s < 7; ++s) {
                if (s < nc) {
                    float t[12];
                    *(float4*)&t[0] = lf[s];
                    *(float4*)&t[4] = lf[s + 1];
                    *(float4*)&t[8] = lf[s + 2];
                    float core = fmaxf(fmaxf(fmaxf(t[3],t[4]), fmaxf(t[5],t[6])), fmaxf(t[7],t[8]));
                    float a12 = fmaxf(t[1], t[2]), a910 = fmaxf(t[9], t[10]);
                    float4 o;
                    o.x = fmaxf(fmaxf(core, a12), t[0]);
                    o.y = fmaxf(fmaxf(core, a12), t[9]);
                    o.z = fmaxf(fmaxf(core, t[2]), a910);
                    o.w = fmaxf(fmaxf(core, a910), t[11]);
                    S[r][c0 + s] = o;
                }
            }
        }
    }
    __syncthreads();

    // ---------------- P2: v-dilate9 in-place (rows 4..37, cols 0..37), reg-staged -----------
    {
        int c = tid % 38, k = tid / 38;
        int ra0 = 4 + 6 * k;
        float4 o[6];
        if (k < 6) {
            float4 w[9];
            #pragma unroll
            for (int q = 0; q < 8; ++q) w[q] = S[ra0 - 4 + q][c];
            #pragma unroll
            for (int s = 0; s < 6; ++s) {
                if (ra0 + s <= 37) {
                    w[8] = S[ra0 + 4 + s][c];
                    float4 m = w[0];
                    #pragma unroll
                    for (int q = 1; q < 9; ++q) m = vmax4(m, w[q]);
                    o[s] = m;
                    #pragma unroll
                    for (int q = 0; q < 8; ++q) w[q] = w[q + 1];
                }
            }
        }
        __syncthreads();
        if (k < 6) {
            #pragma unroll
            for (int s = 0; s < 6; ++s)
                if (ra0 + s <= 37) S[ra0 + s][c] = o[s];
        }
        __syncthreads();
    }

    // ---------------- P3: h-erode5 (rows 4..37, write cols 1..36), reg-staged ---------------
    {
        float4 o[5];
        #pragma unroll
        for (int ii = 0; ii < 5; ++ii) {
            int i = tid + 256 * ii;
            if (i < 34 * 36) {
                int ra = i / 36 + 4, cb = i % 36;
                float t[12];
                *(float4*)&t[0] = S[ra][cb];
                *(float4*)&t[4] = S[ra][cb + 1];
                *(float4*)&t[8] = S[ra][cb + 2];
                if (!interior) {
                    bool rOK = (unsigned)(y0 + ra - 13) < IH;
                    #pragma unroll
                    for (int kk = 2; kk <= 9; ++kk) {
                        int gx = x0 + 4 * cb - 12 + kk;
                        t[kk] = (rOK && (unsigned)gx < IW) ? t[kk] : FLT_MAX;
                    }
                }
                float m34 = fminf(t[3], t[4]), m56 = fminf(t[5], t[6]), m78 = fminf(t[7], t[8]);
                float4 oo;
                oo.x = fminf(fminf(t[2], m34), m56);
                oo.y = fminf(fminf(m34, m56), t[7]);
                oo.z = fminf(fminf(t[4], m56), m78);
                oo.w = fminf(fminf(m56, m78), t[9]);
                o[ii] = oo;
            }
        }
        __syncthreads();
        #pragma unroll
        for (int ii = 0; ii < 5; ++ii) {
            int i = tid + 256 * ii;
            if (i < 34 * 36) { int ra = i / 36 + 4, cb = i % 36; S[ra][cb + 1] = o[ii]; }
        }
        __syncthreads();
    }

    // ---------------- P4: v-erode5 in-place (rows 6..35, cols 1..36), reg-staged ------------
    {
        int c = tid % 36, k = tid / 36;
        int ra0 = 6 + 5 * k;
        float4 o[5];
        if (k < 6) {
            float4 w[5];
            #pragma unroll
            for (int q = 0; q < 4; ++q) w[q] = S[ra0 - 2 + q][c + 1];
            #pragma unroll
            for (int s = 0; s < 5; ++s) {
                w[4] = S[ra0 + 2 + s][c + 1];
                float4 m = w[0];
                #pragma unroll
                for (int q = 1; q < 5; ++q) m = vmin4(m, w[q]);
                o[s] = m;
                #pragma unroll
                for (int q = 0; q < 4; ++q) w[q] = w[q + 1];
            }
        }
        __syncthreads();
        if (k < 6) {
            #pragma unroll
            for (int s = 0; s < 5; ++s) S[ra0 + s][c + 1] = o[s];
        }
        __syncthreads();
    }

    // ---------------- P56: h-dilate7 (regs) + v-dilate7 + fill (rows 9..32, cols 2..35) -----
    {
        int c = tid % 34, k = tid / 34;
        int ra0 = 9 + 4 * k;
        float4 o[4];
        if (k < 6) {
            auto hrow = [&](int rr) -> float4 {
                float t[12];
                *(float4*)&t[0] = S[rr][c + 1];
                *(float4*)&t[4] = S[rr][c + 2];
                *(float4*)&t[8] = S[rr][c + 3];
                if (!interior) {
                    bool rOK = (unsigned)(y0 + rr - 13) < IH;
                    #pragma unroll
                    for (int kk = 1; kk <= 10; ++kk) {
                        int gx = x0 + 4 * c - 8 + kk;
                        t[kk] = (rOK && (unsigned)gx < IW) ? t[kk] : -FLT_MAX;
                    }
                }
                float core = fmaxf(fmaxf(t[4], t[5]), fmaxf(t[6], t[7]));
                float a23 = fmaxf(t[2], t[3]), a89 = fmaxf(t[8], t[9]);
                float4 r;
                r.x = fmaxf(fmaxf(core, a23), t[1]);
                r.y = fmaxf(fmaxf(core, a23), t[8]);
                r.z = fmaxf(fmaxf(core, t[3]), a89);
                r.w = fmaxf(fmaxf(core, a89), t[10]);
                return r;
            };
            float4 hw[7];
            #pragma unroll
            for (int q = 0; q < 6; ++q) hw[q] = hrow(ra0 - 3 + q);
            #pragma unroll
            for (int s = 0; s < 4; ++s) {
                hw[6] = hrow(ra0 + 3 + s);
                float4 m = hw[0];
                #pragma unroll
                for (int q = 1; q < 7; ++q) m = vmax4(m, hw[q]);
                float4 cl = S[ra0 + s][c + 2];
                float4 oo;
                oo.x = cl.x < MIND ? m.x : cl.x;
                oo.y = cl.y < MIND ? m.y : cl.y;
                oo.z = cl.z < MIND ? m.z : cl.z;
                oo.w = cl.w < MIND ? m.w : cl.w;
                o[s] = oo;
                #pragma unroll
                for (int q = 0; q < 6; ++q) hw[q] = hw[q + 1];
            }
        }
        __syncthreads();
        if (k < 6) {
            #pragma unroll
            for (int s = 0; s < 4; ++s) S[ra0 + s][c + 2] = o[s];
        }
        __syncthreads();
    }

    // ---------------- P7: 5x5 median (rows 11..30, cols 2..35), reg-staged ------------------
    {
        int c = tid % 34, k = tid / 34;
        int ra0 = 11 + 3 * k;
        int rlen = (k == 6) ? 2 : 3;
        float4 o[3];
        if (k < 7) {
            float rows_[5][8];
            auto loadrow = [&](float* rw, int rr) {
                float4 q0 = S[rr][c + 1], q1 = S[rr][c + 2], q2 = S[rr][c + 3];
                float tmp[8] = {q0.z, q0.w, q1.x, q1.y, q1.z, q1.w, q2.x, q2.y};
                if (interior) {
                    #pragma unroll
                    for (int j2 = 0; j2 < 8; ++j2) rw[j2] = tmp[j2];
                } else {
                    bool rOK = (unsigned)(y0 + rr - 13) < IH;
                    #pragma unroll
                    for (int j2 = 0; j2 < 8; ++j2) {
                        int gx = x0 + 4 * c - 6 + j2;
                        rw[j2] = (rOK && (unsigned)gx < IW) ? tmp[j2] : 0.0f;
                    }
                }
            };
            #pragma unroll
            for (int q = 0; q < 4; ++q) loadrow(rows_[q], ra0 - 2 + q);
            #pragma unroll
            for (int st = 0; st < 3; ++st) {
                if (st < rlen) {
                    loadrow(rows_[4], ra0 + 2 + st);
                    float cs[8][5];
                    #pragma unroll
                    for (int j2 = 0; j2 < 8; ++j2) {
                        float a0 = rows_[0][j2], a1 = rows_[1][j2], a2 = rows_[2][j2],
                              a3 = rows_[3][j2], a4 = rows_[4][j2];
                        SORT5(a0, a1, a2, a3, a4)
                        cs[j2][0] = a0; cs[j2][1] = a1; cs[j2][2] = a2; cs[j2][3] = a3; cs[j2][4] = a4;
                    }
                    float rr4[4];
                    #pragma unroll
                    for (int p = 0; p < 4; ++p) {
                        float s0,s1,s2,s3,s4,s5,s6,s7,g0,g1,g2,g3,g4;
                        top2_5(cs[p][0],cs[p+1][0],cs[p+2][0],cs[p+3][0],cs[p+4][0], s0, s1);
                        top3_5(cs[p][1],cs[p+1][1],cs[p+2][1],cs[p+3][1],cs[p+4][1], s2, s3, s4);
                        mid3_5(cs[p][2],cs[p+1][2],cs[p+2][2],cs[p+3][2],cs[p+4][2], s5, s6, s7);
                        bot3_5(cs[p][3],cs[p+1][3],cs[p+2][3],cs[p+3][3],cs[p+4][3], g0, g1, g2);
                        bot2_5(cs[p][4],cs[p+1][4],cs[p+2][4],cs[p+3][4],cs[p+4][4], g3, g4);
                        MM8(s0,s1,s2,s3,s4,s5,s6,s7)
                        s0 = g0; s7 = g1;
                        MM8(s0,s1,s2,s3,s4,s5,s6,s7)
                        s0 = g2; s7 = g3;
                        MM8(s0,s1,s2,s3,s4,s5,s6,s7)
                        s0 = g4;
                        MM7(s0,s1,s2,s3,s4,s5,s6)
                        CE(s1,s2) CE(s3,s4) CE(s1,s3) CE(s2,s4)
                        float mn = fminf(s2, s3), mx = fmaxf(s2, s3);
                        rr4[p] = fmaxf(mn, fminf(mx, s5));
                    }
                    o[st] = make_float4(rr4[0], rr4[1], rr4[2], rr4[3]);
                    #pragma unroll
                    for (int q = 0; q < 4; ++q) {
                        #pragma unroll
                        for (int q2 = 0; q2 < 8; ++q2) rows_[q][q2] = rows_[q + 1][q2];
                    }
                }
            }
        }
        __syncthreads();
        if (k < 7) {
            #pragma unroll
            for (int st = 0; st < 3; ++st)
                if (st < rlen) S[ra0 + st][c + 2] = o[st];
        }
        __syncthreads();
    }

    // ---------------- P89: h-gauss (regs) + v-gauss + select + invert + store ---------------
    {
        int c = tid % 32, k = tid / 32;
        int ra0 = 13 + 2 * k;
        bool lfix = (tx == 0) && (c == 0);
        bool rfix = (tx == 9) && (c == 15);
        auto hgrow = [&](int rr) -> float4 {
            float4 q0 = S[rr][c + 2], q1 = S[rr][c + 3], q2 = S[rr][c + 4];
            float t[8] = {q0.z, q0.w, q1.x, q1.y, q1.z, q1.w, q2.x, q2.y};
            if (lfix) { t[0] = t[4]; t[1] = t[3]; }
            if (rfix) { t[6] = t[4]; t[7] = t[3]; }
            float4 r;
            r.x = w2 * (t[0] + t[4]) + w1 * (t[1] + t[3]) + w0 * t[2];
            r.y = w2 * (t[1] + t[5]) + w1 * (t[2] + t[4]) + w0 * t[3];
            r.z = w2 * (t[2] + t[6]) + w1 * (t[3] + t[5]) + w0 * t[4];
            r.w = w2 * (t[3] + t[7]) + w1 * (t[4] + t[6]) + w0 * t[5];
            return r;
        };
        float4 hw[6];
        #pragma unroll
        for (int q = 0; q < 6; ++q) hw[q] = hgrow(ra0 - 2 + q);
        bool ybt = (ty == 0) || (ty == 21);
        int gx4 = xb4 + c;
        #pragma unroll
        for (int s = 0; s < 2; ++s) {
            int ra = ra0 + s;
            int gy = y0 + ra - 13;
            float4 bl;
            if (!ybt) {
                bl.x = w2 * (hw[s].x + hw[s+4].x) + w1 * (hw[s+1].x + hw[s+3].x) + w0 * hw[s+2].x;
                bl.y = w2 * (hw[s].y + hw[s+4].y) + w1 * (hw[s+1].y + hw[s+3].y) + w0 * hw[s+2].y;
                bl.z = w2 * (hw[s].z + hw[s+4].z) + w1 * (hw[s+1].z + hw[s+3].z) + w0 * hw[s+2].z;
                bl.w = w2 * (hw[s].w + hw[s+4].w) + w1 * (hw[s+1].w + hw[s+3].w) + w0 * hw[s+2].w;
            } else {
                float we0 = w2, we1 = w1, we2 = w0, we3 = w1, we4 = w2;
                if (gy == 0)        { we0 = 0; we1 = 0; we3 = 2*w1; we4 = 2*w2; }
                else if (gy == 1)   { we0 = 0; we2 = w0 + w2; }
                else if (gy == 350) { we2 = w0 + w2; we4 = 0; }
                else if (gy == 351) { we0 = 2*w2; we1 = 2*w1; we3 = 0; we4 = 0; }
                bl.x = we0*hw[s].x + we1*hw[s+1].x + we2*hw[s+2].x + we3*hw[s+3].x + we4*hw[s+4].x;
                bl.y = we0*hw[s].y + we1*hw[s+1].y + we2*hw[s+2].y + we3*hw[s+3].y + we4*hw[s+4].y;
                bl.z = we0*hw[s].z + we1*hw[s+1].z + we2*hw[s+2].z + we3*hw[s+3].z + we4*hw[s+4].z;
                bl.w = we0*hw[s].w + we1*hw[s+1].w + we2*hw[s+2].w + we3*hw[s+3].w + we4*hw[s+4].w;
            }
            float4 dm = S[ra][c + 3];
            float4 oo;
            { float sv = dm.x > MIND ? bl.x : dm.x; oo.x = sv > MIND ? MAXD - sv : sv; }
            { float sv = dm.y > MIND ? bl.y : dm.y; oo.y = sv > MIND ? MAXD - sv : sv; }
            { float sv = dm.z > MIND ? bl.z : dm.z; oo.z = sv > MIND ? MAXD - sv : sv; }
            { float sv = dm.w > MIND ? bl.w : dm.w; oo.w = sv > MIND ? MAXD - sv : sv; }
            if (gx4 < W4) out[ib + (long)gy * W4 + gx4] = oo;
        }
    }
}

extern "C" void kernel_launch(void* const* d_in, const int* in_sizes, int n_in,
                              void* d_out, int out_size, void* d_ws, size_t ws_size,
                              hipStream_t stream) {
    const float4* in = (const float4*)d_in[0];
    float4* O = (float4*)d_out;

    // Gaussian weights: sigma = 1.1 -> 2*sigma^2 = 2.42
    float c2 = 2.42f;
    float e1 = expf(-1.0f / c2);
    float e4 = expf(-4.0f / c2);
    float s  = 1.0f + 2.0f * e1 + 2.0f * e4;
    float w0 = 1.0f / s, w1 = e1 / s, w2 = e4 / s;

    mega_k<<<dim3(3520), dim3(256), 0, stream>>>(in, O, w0, w1, w2);
}